// Round 6
// baseline (204.764 us; speedup 1.0000x reference)
//
#include <hip/hip_runtime.h>

// GPT-2 attention block, B=4 S=2048 D=1024 H=16 DH=64, f32 in/out.
// GEMMs: 16x16x32 bf16 MFMA, 8-wave blocks, QKV 256x256 / proj 128x256 tiles,
//        3-buffer counted-vmcnt single-barrier pipeline, source-swizzled gll16.
// Attention: 32x32x16 bf16 MFMA, swapped operands, in-register softmax,
//        gll16 DMA staging (source-swizzled), raw-barrier double buffer.
// Layouts (gfx950):
//   16x16x32: A[l&15][8*(l>>4)+e], B[l&15][8*(l>>4)+e], D[4*(l>>4)+r][l&15]
//   32x32x16: A[l&31][8*(l>>5)+e], B[l&31][8*(l>>5)+e],
//             D[(r&3)+8*(r>>2)+4*(l>>5)][l&31]

typedef short  s8v   __attribute__((ext_vector_type(8)));  // 8 bf16 (16B)
typedef float  f32x4 __attribute__((ext_vector_type(4)));
typedef float  f32x16 __attribute__((ext_vector_type(16)));
typedef unsigned short u16;
typedef u16    u16x4 __attribute__((ext_vector_type(4)));
typedef unsigned int u32;
typedef u32    u32x2 __attribute__((ext_vector_type(2)));

__device__ __forceinline__ u16 f2b(float f) {
  union { float f; unsigned u; } v; v.f = f;
  unsigned r = v.u + 0x7FFFu + ((v.u >> 16) & 1u);   // RNE
  return (u16)(r >> 16);
}
__device__ __forceinline__ u32 cvtpk(float lo, float hi) {   // bf16(lo)|bf16(hi)<<16
  u32 r; asm("v_cvt_pk_bf16_f32 %0, %1, %2" : "=v"(r) : "v"(lo), "v"(hi)); return r;
}
__device__ __forceinline__ void plswap(u32 &d, u32 &s) {
  asm volatile("v_permlane32_swap_b32 %0, %1" : "+v"(d), "+v"(s));
}
__device__ __forceinline__ void gll16(const void* g, void* l) {
  __builtin_amdgcn_global_load_lds((const __attribute__((address_space(1))) void*)g,
                                   (__attribute__((address_space(3))) void*)l, 16, 0, 0);
}

#define QSCALE 0.18033688011112042f   // 0.125 * log2(e): softmax in exp2 domain

// ---------------- f32 -> bf16 elementwise ----------------
__global__ __launch_bounds__(256) void k_cvt(const float* __restrict__ in,
                                             u16* __restrict__ out, int n4) {
  int t = blockIdx.x * 256 + threadIdx.x;
  if (t < n4) {
    f32x4 f = ((const f32x4*)in)[t];
    u16x4 o;
    o[0] = f2b(f[0]); o[1] = f2b(f[1]); o[2] = f2b(f[2]); o[3] = f2b(f[3]);
    ((u16x4*)out)[t] = o;
  }
}

// ---------------- f32 [R][C] -> bf16 [C][R] transpose ----------------
__global__ __launch_bounds__(256) void k_tr(const float* __restrict__ in,
                                            u16* __restrict__ out, int R, int C) {
  __shared__ float tile[32][33];
  int c0 = blockIdx.x * 32, r0 = blockIdx.y * 32;
  int tx = threadIdx.x, ty = threadIdx.y;
#pragma unroll
  for (int j = 0; j < 4; j++)
    tile[ty + j * 8][tx] = in[(size_t)(r0 + ty + j * 8) * C + c0 + tx];
  __syncthreads();
#pragma unroll
  for (int j = 0; j < 4; j++)
    out[(size_t)(c0 + ty + j * 8) * R + r0 + tx] = f2b(tile[tx][ty + j * 8]);
}

// ---------------- bf16 GEMM: C[M,N] = A[M,K] @ Bt[N,K]^T (+bias) ----------------
// BM x BN tile, BK=32, 512 threads = 8 waves (2M x 4N). 3 LDS buffers, 1 raw
// barrier + counted vmcnt per tile (2-tile lookahead). Source-swizzled gll16.
// EPI 0: scatter q/k [bh][S][64] (q pre-scaled), v transposed [bh][64][S].
// EPI 1: f32 out.
template <int EPI, int BM, int BN, int MINW>
__global__ __launch_bounds__(512, MINW) void k_gemm(
    const u16* __restrict__ A, const u16* __restrict__ Bt,
    const float* __restrict__ bias,
    u16* __restrict__ qb, u16* __restrict__ kb, u16* __restrict__ vb,
    float* __restrict__ outf, int M, int N, int K) {
  constexpr int MF = BM / 32;      // m-frags per wave
  constexpr int NF = BN / 64;      // n-frags per wave
  constexpr int AS = BM / 128;     // A staging sweeps per wave
  constexpr int BS = BN / 128;     // B staging sweeps per wave
  constexpr int LPW = AS + BS;     // gll16 per wave per tile
  __shared__ u16 lA[3][BM * 32];   // [buf][rows][32 cols], 16B-cell swizzled
  __shared__ u16 lB[3][BN * 32];
  const int tid = threadIdx.x;
  const int lane = tid & 63, w = tid >> 6;
  const int wr = (w >> 2) * (BM / 2), wc = (w & 3) * (BN / 4);
  const int lr = lane & 15, lg = lane >> 4;

  // XCD-chunked block swizzle (nwg % 8 == 0 for both shapes)
  const int nwg = gridDim.x * gridDim.y;
  const int bid = blockIdx.y * gridDim.x + blockIdx.x;
  const int swz = (bid & 7) * (nwg >> 3) + (bid >> 3);
  const int m0 = (swz / gridDim.x) * BM, n0 = (swz % gridDim.x) * BN;

  // staging: sweep sg covers LDS cells [64sg, 64sg+64); lane l holds global
  // (row = 16sg + l/4, slot = (l&3)^((l>>3)&3))  [inverse of read swizzle]
  const int rr = lane >> 2;
  const int cb = ((lane & 3) ^ ((lane >> 3) & 3)) * 16;    // byte col in 64B row
  const size_t K2 = (size_t)K * 2;
  const char* gAc = (const char*)A + (size_t)m0 * K2;
  const char* gBc = (const char*)Bt + (size_t)n0 * K2;

  auto stage = [&](int kt, int buf) {
    const size_t ko = (size_t)kt * 64 + cb;
    char* dA = (char*)&lA[buf][0];
    char* dB = (char*)&lB[buf][0];
#pragma unroll
    for (int i = 0; i < AS; i++) {
      const int sg = AS * w + i;
      gll16(gAc + (size_t)(16 * sg + rr) * K2 + ko, dA + sg * 1024);
    }
#pragma unroll
    for (int i = 0; i < BS; i++) {
      const int sg = BS * w + i;
      gll16(gBc + (size_t)(16 * sg + rr) * K2 + ko, dB + sg * 1024);
    }
  };

  auto tile_compute = [&](const u16* bA, const u16* bB, f32x4 (&acc)[MF][NF]) {
    s8v af[MF], bfr[NF];
#pragma unroll
    for (int m = 0; m < MF; m++) {
      const int row = wr + m * 16 + lr;
      af[m] = *(const s8v*)&bA[row * 32 + (lg ^ ((row >> 1) & 3)) * 8];
    }
#pragma unroll
    for (int n = 0; n < NF; n++) {
      const int row = wc + n * 16 + lr;
      bfr[n] = *(const s8v*)&bB[row * 32 + (lg ^ ((row >> 1) & 3)) * 8];
    }
    __builtin_amdgcn_s_setprio(1);
#pragma unroll
    for (int m = 0; m < MF; m++)
#pragma unroll
      for (int n = 0; n < NF; n++)
        acc[m][n] = __builtin_amdgcn_mfma_f32_16x16x32_bf16(af[m], bfr[n], acc[m][n], 0, 0, 0);
    __builtin_amdgcn_s_setprio(0);
  };

  f32x4 acc[MF][NF];
  f32x4 zz = {0.f, 0.f, 0.f, 0.f};
#pragma unroll
  for (int m = 0; m < MF; m++)
#pragma unroll
    for (int n = 0; n < NF; n++) acc[m][n] = zz;

  const int nk = K / 32;
  stage(0, 0);
  if (nk > 1) stage(1, 1);

#define STEP(T, CB, SB)                                                      \
  if ((T) < nk) {                                                            \
    if ((T) + 1 < nk) {                                                      \
      if constexpr (LPW == 4) asm volatile("s_waitcnt vmcnt(4)" ::: "memory"); \
      else                    asm volatile("s_waitcnt vmcnt(3)" ::: "memory"); \
    } else {                                                                 \
      asm volatile("s_waitcnt vmcnt(0)" ::: "memory");                       \
    }                                                                        \
    __builtin_amdgcn_s_barrier();                                            \
    __builtin_amdgcn_sched_barrier(0);                                       \
    if ((T) + 2 < nk) stage((T) + 2, (SB));                                  \
    tile_compute(&lA[(CB)][0], &lB[(CB)][0], acc);                           \
  }

  for (int t0 = 0; t0 < nk; t0 += 3) {
    STEP(t0,     0, 2)
    STEP(t0 + 1, 1, 0)
    STEP(t0 + 2, 2, 1)
  }
#undef STEP

#pragma unroll
  for (int m = 0; m < MF; m++) {
#pragma unroll
    for (int n = 0; n < NF; n++) {
      const int col = n0 + wc + n * 16 + lr;
      const float bb = bias[col];
      const int row0 = m0 + wr + m * 16 + 4 * lg;
      if (EPI == 0) {
        const int which = col >> 10, d = col & 1023, h = d >> 6, dh = d & 63;
        if (which == 2) {
          const int b = row0 >> 11, s = row0 & 2047;
          u16x4 ov;
#pragma unroll
          for (int r = 0; r < 4; r++) ov[r] = f2b(acc[m][n][r] + bb);
          *(u16x4*)(vb + ((size_t)((b * 16 + h) * 64 + dh)) * 2048 + s) = ov;
        } else {
          u16* dst = which == 0 ? qb : kb;
          const float sc = which == 0 ? QSCALE : 1.0f;
#pragma unroll
          for (int r = 0; r < 4; r++) {
            const int row = row0 + r;
            const int b = row >> 11, s = row & 2047;
            dst[(size_t)((b * 16 + h) * 2048 + s) * 64 + dh] = f2b((acc[m][n][r] + bb) * sc);
          }
        }
      } else {
#pragma unroll
        for (int r = 0; r < 4; r++)
          outf[(size_t)(row0 + r) * N + col] = acc[m][n][r] + bb;
      }
    }
  }
}

// ---------------- flash attention, causal, swapped 32x32 MFMA, in-reg softmax ----
// grid 1024 = (bh,qt), LPT, bh-group per XCD. K/V staged via gll16 DMA with
// source-side swizzle: K cell(sl,r)=sl*64+(r^sl) -> sweep sg, lane l <- row l^sg.
__global__ __launch_bounds__(256, 3) void k_attn(
    const u16* __restrict__ Q, const u16* __restrict__ K,
    const u16* __restrict__ Vt, u16* __restrict__ O) {
  __shared__ u16 lKV[2][8192];     // [buf][ K: 4096 u16 | V: 4096 u16 ]
  const int x = blockIdx.x;
  const int bh = ((x & 7) << 3) | ((x >> 3) & 7);
  const int qt = 15 - (x >> 6);
  const int tid = threadIdx.x, lane = tid & 63, w = tid >> 6;
  const int l31 = lane & 31, h = lane >> 5;
  const int qbase = qt * 128 + w * 32;
  const u16* Kb = K + (size_t)bh * 2048 * 64;
  const u16* Vb = Vt + (size_t)bh * 64 * 2048;

  auto stage_dma = [&](int kv0, int buf) {
    char* base = (char*)&lKV[buf][0];
#pragma unroll
    for (int i = 0; i < 2; i++) {
      const int sg = 2 * w + i;            // sweeps 0..7 across 4 waves, x2 (K,V)
      const int r = lane ^ sg;
      gll16(Kb + (size_t)(kv0 + r) * 64 + sg * 8, base + sg * 1024);
      gll16(Vb + (size_t)r * 2048 + kv0 + sg * 8, base + 8192 + sg * 1024);
    }
  };

  // Q B-frags: lane l -> q col = l31, k(dh) = ks*16 + 8h + e
  s8v qf[4];
#pragma unroll
  for (int ks = 0; ks < 4; ks++)
    qf[ks] = *(const s8v*)(Q + (size_t)(bh * 2048 + qbase + l31) * 64 + ks * 16 + 8 * h);

  f32x16 accO0, accO1;
#pragma unroll
  for (int i = 0; i < 16; i++) { accO0[i] = 0.f; accO1[i] = 0.f; }
  float mrun = -1e30f, lrun = 0.f;

  const int ntile = 2 * qt + 2;
  stage_dma(0, 0);

  for (int t = 0; t < ntile; ++t) {
    const int kv0 = t * 64;
    asm volatile("s_waitcnt vmcnt(0)" ::: "memory");   // buf[t&1] DMA complete
    __builtin_amdgcn_s_barrier();
    __builtin_amdgcn_sched_barrier(0);
    if (t + 1 < ntile) stage_dma((t + 1) * 64, (t + 1) & 1);
    const u16* base = &lKV[t & 1][0];

    if (kv0 <= qbase + 31) {               // wave-uniform causal skip
      // ---- swapped QK^T: S^T[kv][q], one q column per lane ----
      f32x16 st0, st1;
#pragma unroll
      for (int i = 0; i < 16; i++) { st0[i] = 0.f; st1[i] = 0.f; }
      __builtin_amdgcn_s_setprio(1);
#pragma unroll
      for (int ks = 0; ks < 4; ks++) {
        const int sl = 2 * ks + h;
        s8v a0 = *(const s8v*)&base[(sl * 64 + (l31 ^ sl)) * 8];
        s8v a1 = *(const s8v*)&base[(sl * 64 + ((32 + l31) ^ sl)) * 8];
        st0 = __builtin_amdgcn_mfma_f32_32x32x16_bf16(a0, qf[ks], st0, 0, 0, 0);
        st1 = __builtin_amdgcn_mfma_f32_32x32x16_bf16(a1, qf[ks], st1, 0, 0, 0);
      }
      __builtin_amdgcn_s_setprio(0);
      // ---- causal mask (diagonal tiles only) ----
      if (kv0 + 63 > qbase) {
        const int dq = qbase + l31 - kv0;  // kv_local <= dq allowed
#pragma unroll
        for (int r = 0; r < 16; r++) {
          const int kl = (r & 3) + 8 * (r >> 2) + 4 * h;
          if (kl > dq) st0[r] = -1e30f;
          if (kl + 32 > dq) st1[r] = -1e30f;
        }
      }
      // ---- online softmax, defer-max (T13) ----
      float mx = st0[0];
#pragma unroll
      for (int r = 1; r < 16; r++) mx = fmaxf(mx, st0[r]);
#pragma unroll
      for (int r = 0; r < 16; r++) mx = fmaxf(mx, st1[r]);
      mx = fmaxf(mx, __shfl_xor(mx, 32));
      if (!__all(mx <= mrun + 11.0f)) {
        const float mnew = fmaxf(mrun, mx);
        const float f = exp2f(mrun - mnew);
        lrun *= f;
#pragma unroll
        for (int r = 0; r < 16; r++) { accO0[r] *= f; accO1[r] *= f; }
        mrun = mnew;
      }
      float s = 0.f;
#pragma unroll
      for (int r = 0; r < 16; r++) { st0[r] = exp2f(st0[r] - mrun); s += st0[r]; }
#pragma unroll
      for (int r = 0; r < 16; r++) { st1[r] = exp2f(st1[r] - mrun); s += st1[r]; }
      s += __shfl_xor(s, 32);
      lrun += s;
      // ---- P -> bf16 in-register ----
      u32 W0[8], W1[8];
#pragma unroll
      for (int a = 0; a < 4; a++) {
        W0[2 * a]     = cvtpk(st0[4 * a], st0[4 * a + 1]);
        W0[2 * a + 1] = cvtpk(st0[4 * a + 2], st0[4 * a + 3]);
        W1[2 * a]     = cvtpk(st1[4 * a], st1[4 * a + 1]);
        W1[2 * a + 1] = cvtpk(st1[4 * a + 2], st1[4 * a + 3]);
      }
      // ---- PV: O^T[dh][q] += Vt @ P, B-frag via permlane32_swap ----
      __builtin_amdgcn_s_setprio(1);
#pragma unroll
      for (int ks = 0; ks < 4; ks++) {
        const int kp = ks & 1;
        u32 x0 = (ks < 2) ? W0[4 * kp]     : W1[4 * kp];
        u32 y0 = (ks < 2) ? W0[4 * kp + 2] : W1[4 * kp + 2];
        u32 x1 = (ks < 2) ? W0[4 * kp + 1] : W1[4 * kp + 1];
        u32 y1 = (ks < 2) ? W0[4 * kp + 3] : W1[4 * kp + 3];
        plswap(x0, y0);
        plswap(x1, y1);
        union { u32 u[4]; s8v v; } fb;
        fb.u[0] = x0; fb.u[1] = x1; fb.u[2] = y0; fb.u[3] = y1;
        const int sl = 2 * ks + h;
        s8v va0 = *(const s8v*)&base[4096 + (sl * 64 + (l31 ^ sl)) * 8];
        s8v va1 = *(const s8v*)&base[4096 + (sl * 64 + ((32 + l31) ^ sl)) * 8];
        accO0 = __builtin_amdgcn_mfma_f32_32x32x16_bf16(va0, fb.v, accO0, 0, 0, 0);
        accO1 = __builtin_amdgcn_mfma_f32_32x32x16_bf16(va1, fb.v, accO1, 0, 0, 0);
      }
      __builtin_amdgcn_s_setprio(0);
    }
  }

  // ---- epilogue: O = O^T / l, merge heads, 8B stores ----
  const int b_ = bh >> 4, h_ = bh & 15;
  const float rinv = 1.0f / lrun;
  u16* Ob = O + (size_t)(b_ * 2048 + qbase + l31) * 1024 + h_ * 64;
#pragma unroll
  for (int a = 0; a < 4; a++) {
    u32x2 o0, o1;
    o0[0] = cvtpk(accO0[4 * a] * rinv, accO0[4 * a + 1] * rinv);
    o0[1] = cvtpk(accO0[4 * a + 2] * rinv, accO0[4 * a + 3] * rinv);
    o1[0] = cvtpk(accO1[4 * a] * rinv, accO1[4 * a + 1] * rinv);
    o1[1] = cvtpk(accO1[4 * a + 2] * rinv, accO1[4 * a + 3] * rinv);
    *(u32x2*)(Ob + 8 * a + 4 * h) = o0;
    *(u32x2*)(Ob + 32 + 8 * a + 4 * h) = o1;
  }
}

extern "C" void kernel_launch(void* const* d_in, const int* in_sizes, int n_in,
                              void* d_out, int out_size, void* d_ws, size_t ws_size,
                              hipStream_t stream) {
  const float* x      = (const float*)d_in[0];
  const float* w_attn = (const float*)d_in[1];
  const float* b_attn = (const float*)d_in[2];
  const float* w_proj = (const float*)d_in[3];
  const float* b_proj = (const float*)d_in[4];
  float* out = (float*)d_out;

  u16* ws  = (u16*)d_ws;
  u16* xb  = ws;                   // x bf16 [8192][1024]; reused as attn-out
  u16* wTa = xb + 8388608;         // w_attn^T bf16 [3072][1024]
  u16* wTp = wTa + 3145728;        // w_proj^T bf16 [1024][1024]
  u16* qb  = wTp + 1048576;        // [64 bh][2048][64], pre-scaled 0.125*log2e
  u16* kb  = qb + 8388608;         // [64 bh][2048][64]
  u16* vb  = kb + 8388608;         // [64 bh][64][2048]  (transposed)

  k_cvt<<<8192, 256, 0, stream>>>(x, xb, 2097152);
  k_tr<<<dim3(96, 32), dim3(32, 8), 0, stream>>>(w_attn, wTa, 1024, 3072);
  k_tr<<<dim3(32, 32), dim3(32, 8), 0, stream>>>(w_proj, wTp, 1024, 1024);
  // QKV: 256x256 tile, grid 12x32 = 384 blocks (1 block/CU, 8 waves)
  k_gemm<0, 256, 256, 2><<<dim3(12, 32), 512, 0, stream>>>(
      xb, wTa, b_attn, qb, kb, vb, nullptr, 8192, 3072, 1024);
  k_attn<<<1024, 256, 0, stream>>>(qb, kb, vb, xb);
  // proj: 128x256 tile, grid 4x64 = 256 blocks (2 blocks/CU capacity)
  k_gemm<1, 128, 256, 4><<<dim3(4, 64), 512, 0, stream>>>(
      xb, wTp, b_proj, nullptr, nullptr, nullptr, out, 8192, 1024, 1024);
}

// Round 7
// 189.297 us; speedup vs baseline: 1.0817x; 1.0817x over previous
//
#include <hip/hip_runtime.h>

// GPT-2 attention block, B=4 S=2048 D=1024 H=16 DH=64, f32 in/out.
// GEMMs: 16x16x32 bf16 MFMA, 256x128 tile BK=64, 8 waves (4Mx2N), 3-buffer
//        counted-vmcnt + 2-phase-per-K-step schedule (T3/T4/T5), source-side
//        XOR-swizzled gll16 staging (slot ^= row&7 within 128B rows).
// Attention: 32x32x16 bf16 MFMA, swapped operands, in-register softmax,
//        gll16 DMA staging (source-swizzled), raw-barrier double buffer.
// Layouts (gfx950):
//   16x16x32: A[l&15][8*(l>>4)+e], B[l&15][8*(l>>4)+e], D[4*(l>>4)+r][l&15]
//   32x32x16: A[l&31][8*(l>>5)+e], B[l&31][8*(l>>5)+e],
//             D[(r&3)+8*(r>>2)+4*(l>>5)][l&31]

typedef short  s8v   __attribute__((ext_vector_type(8)));  // 8 bf16 (16B)
typedef float  f32x4 __attribute__((ext_vector_type(4)));
typedef float  f32x16 __attribute__((ext_vector_type(16)));
typedef unsigned short u16;
typedef u16    u16x4 __attribute__((ext_vector_type(4)));
typedef unsigned int u32;
typedef u32    u32x2 __attribute__((ext_vector_type(2)));

__device__ __forceinline__ u16 f2b(float f) {
  union { float f; unsigned u; } v; v.f = f;
  unsigned r = v.u + 0x7FFFu + ((v.u >> 16) & 1u);   // RNE
  return (u16)(r >> 16);
}
__device__ __forceinline__ u32 cvtpk(float lo, float hi) {   // bf16(lo)|bf16(hi)<<16
  u32 r; asm("v_cvt_pk_bf16_f32 %0, %1, %2" : "=v"(r) : "v"(lo), "v"(hi)); return r;
}
__device__ __forceinline__ void plswap(u32 &d, u32 &s) {
  asm volatile("v_permlane32_swap_b32 %0, %1" : "+v"(d), "+v"(s));
}
__device__ __forceinline__ void gll16(const void* g, void* l) {
  __builtin_amdgcn_global_load_lds((const __attribute__((address_space(1))) void*)g,
                                   (__attribute__((address_space(3))) void*)l, 16, 0, 0);
}

#define QSCALE 0.18033688011112042f   // 0.125 * log2(e): softmax in exp2 domain

// ---------------- f32 -> bf16 elementwise ----------------
__global__ __launch_bounds__(256) void k_cvt(const float* __restrict__ in,
                                             u16* __restrict__ out, int n4) {
  int t = blockIdx.x * 256 + threadIdx.x;
  if (t < n4) {
    f32x4 f = ((const f32x4*)in)[t];
    u16x4 o;
    o[0] = f2b(f[0]); o[1] = f2b(f[1]); o[2] = f2b(f[2]); o[3] = f2b(f[3]);
    ((u16x4*)out)[t] = o;
  }
}

// ---------------- f32 [R][C] -> bf16 [C][R] transpose ----------------
__global__ __launch_bounds__(256) void k_tr(const float* __restrict__ in,
                                            u16* __restrict__ out, int R, int C) {
  __shared__ float tile[32][33];
  int c0 = blockIdx.x * 32, r0 = blockIdx.y * 32;
  int tx = threadIdx.x, ty = threadIdx.y;
#pragma unroll
  for (int j = 0; j < 4; j++)
    tile[ty + j * 8][tx] = in[(size_t)(r0 + ty + j * 8) * C + c0 + tx];
  __syncthreads();
#pragma unroll
  for (int j = 0; j < 4; j++)
    out[(size_t)(c0 + ty + j * 8) * R + r0 + tx] = f2b(tile[tx][ty + j * 8]);
}

// ---------------- bf16 GEMM: C[M,N] = A[M,K] @ Bt[N,K]^T (+bias) ----------------
// BM=256, BN=128, BK=64, 512 threads = 8 waves (4M x 2N, wave tile 64x64).
// 3 LDS buffers; per K-step: [vmcnt(6); barrier] then 2 phases of
// {3 gll16(t+2) | 8 ds_read | lgkmcnt0 | 16 MFMA | barrier}.
// EPI 0: scatter q/k [bh][S][64] (q pre-scaled), v transposed [bh][64][S].
// EPI 1: f32 out.
template <int EPI, int KT>
__global__ __launch_bounds__(512, 2) void k_gemm(
    const u16* __restrict__ A, const u16* __restrict__ Bt,
    const float* __restrict__ bias,
    u16* __restrict__ qb, u16* __restrict__ kb, u16* __restrict__ vb,
    float* __restrict__ outf, int M, int N) {
  __shared__ u16 lA[3][256 * 64];   // [buf][row][64 cols], slot^=(row&7) swizzle
  __shared__ u16 lB[3][128 * 64];
  const int tid = threadIdx.x;
  const int lane = tid & 63, w = tid >> 6;
  const int wr = (w >> 1) * 64, wc = (w & 1) * 64;
  const int lr = lane & 15, lg = lane >> 4;

  // XCD-chunked block swizzle (nwg % 8 == 0 for both shapes)
  const int nwg = gridDim.x * gridDim.y;
  const int bid = blockIdx.y * gridDim.x + blockIdx.x;
  const int swz = (bid & 7) * (nwg >> 3) + (bid >> 3);
  const int m0 = (swz / gridDim.x) * 256, n0 = (swz % gridDim.x) * 128;

  // staging: sweep sg = LDS bytes [1024 sg, +1024) = rows 8sg..8sg+7 (128B/row).
  // lane l -> row 8sg+(l>>3), phys 16B-slot l&7, which holds logical slot
  // (l&7)^(row&7) = (l&7)^(l>>3)  ->  global u16 col ((l&7)^(l>>3))*8.
  const size_t K2 = (size_t)KT * 2;
  const char* gAc = (const char*)A + (size_t)m0 * K2 + (size_t)(lane >> 3) * K2 +
                    (((lane & 7) ^ (lane >> 3)) * 16);
  const char* gBc = (const char*)Bt + (size_t)n0 * K2 + (size_t)(lane >> 3) * K2 +
                    (((lane & 7) ^ (lane >> 3)) * 16);

  auto gllA = [&](int kt, int buf, int i) {
    const int sg = 4 * w + i;                 // 32 A-sweeps across 8 waves
    gll16(gAc + (size_t)sg * 8 * K2 + (size_t)kt * 128,
          (char*)&lA[buf][0] + sg * 1024);
  };
  auto gllB = [&](int kt, int buf, int i) {
    const int sg = 2 * w + i;                 // 16 B-sweeps across 8 waves
    gll16(gBc + (size_t)sg * 8 * K2 + (size_t)kt * 128,
          (char*)&lB[buf][0] + sg * 1024);
  };

  f32x4 acc[4][4];
  f32x4 zz = {0.f, 0.f, 0.f, 0.f};
#pragma unroll
  for (int m = 0; m < 4; m++)
#pragma unroll
    for (int n = 0; n < 4; n++) acc[m][n] = zz;

  // one phase: 8 swizzled ds_read_b128 + 16 MFMA at K-slice ks, then barrier
  auto phase = [&](const u16* bA, const u16* bB, int ks) {
    s8v af[4], bf[4];
#pragma unroll
    for (int n = 0; n < 4; n++) {
      const int row = wc + n * 16 + lr;
      bf[n] = *(const s8v*)&bB[row * 64 + (((ks << 2) | lg) ^ (row & 7)) * 8];
    }
#pragma unroll
    for (int m = 0; m < 4; m++) {
      const int row = wr + m * 16 + lr;
      af[m] = *(const s8v*)&bA[row * 64 + (((ks << 2) | lg) ^ (row & 7)) * 8];
    }
    asm volatile("s_waitcnt lgkmcnt(0)" ::: "memory");
    __builtin_amdgcn_sched_barrier(0);
    __builtin_amdgcn_s_setprio(1);
#pragma unroll
    for (int m = 0; m < 4; m++)
#pragma unroll
      for (int n = 0; n < 4; n++)
        acc[m][n] = __builtin_amdgcn_mfma_f32_16x16x32_bf16(af[m], bf[n], acc[m][n], 0, 0, 0);
    __builtin_amdgcn_s_setprio(0);
    __builtin_amdgcn_s_barrier();
  };

  constexpr int nk = KT / 64;        // 16
  // prologue: stage steps 0 and 1 (6 loads each)
  gllA(0, 0, 0); gllA(0, 0, 1); gllA(0, 0, 2); gllA(0, 0, 3);
  gllB(0, 0, 0); gllB(0, 0, 1);
  gllA(1, 1, 0); gllA(1, 1, 1); gllA(1, 1, 2); gllA(1, 1, 3);
  gllB(1, 1, 0); gllB(1, 1, 1);

#define STEP(T, CB, SB)                                                        \
  if ((T) < nk) {                                                              \
    if ((T) + 1 < nk) asm volatile("s_waitcnt vmcnt(6)" ::: "memory");         \
    else              asm volatile("s_waitcnt vmcnt(0)" ::: "memory");         \
    __builtin_amdgcn_s_barrier();                                              \
    __builtin_amdgcn_sched_barrier(0);                                         \
    if ((T) + 2 < nk) { gllA((T)+2,(SB),0); gllA((T)+2,(SB),1); gllB((T)+2,(SB),0); } \
    phase(&lA[(CB)][0], &lB[(CB)][0], 0);                                      \
    if ((T) + 2 < nk) { gllA((T)+2,(SB),2); gllA((T)+2,(SB),3); gllB((T)+2,(SB),1); } \
    phase(&lA[(CB)][0], &lB[(CB)][0], 1);                                      \
  }

#pragma unroll
  for (int t0 = 0; t0 < nk; t0 += 3) {
    STEP(t0,     0, 2)
    STEP(t0 + 1, 1, 0)
    STEP(t0 + 2, 2, 1)
  }
#undef STEP

#pragma unroll
  for (int m = 0; m < 4; m++) {
#pragma unroll
    for (int n = 0; n < 4; n++) {
      const int col = n0 + wc + n * 16 + lr;
      const float bb = bias[col];
      const int row0 = m0 + wr + m * 16 + 4 * lg;
      if (EPI == 0) {
        const int which = col >> 10, d = col & 1023, h = d >> 6, dh = d & 63;
        if (which == 2) {
          const int b = row0 >> 11, s = row0 & 2047;
          u16x4 ov;
#pragma unroll
          for (int r = 0; r < 4; r++) ov[r] = f2b(acc[m][n][r] + bb);
          *(u16x4*)(vb + ((size_t)((b * 16 + h) * 64 + dh)) * 2048 + s) = ov;
        } else {
          u16* dst = which == 0 ? qb : kb;
          const float sc = which == 0 ? QSCALE : 1.0f;
#pragma unroll
          for (int r = 0; r < 4; r++) {
            const int row = row0 + r;
            const int b = row >> 11, s = row & 2047;
            dst[(size_t)((b * 16 + h) * 2048 + s) * 64 + dh] = f2b((acc[m][n][r] + bb) * sc);
          }
        }
      } else {
#pragma unroll
        for (int r = 0; r < 4; r++)
          outf[(size_t)(row0 + r) * N + col] = acc[m][n][r] + bb;
      }
    }
  }
}

// ---------------- flash attention, causal, swapped 32x32 MFMA, in-reg softmax ----
// grid 1024 = (bh,qt), LPT, bh-group per XCD. K/V staged via gll16 DMA with
// source-side swizzle: K cell(sl,r)=sl*64+(r^sl) -> sweep sg, lane l <- row l^sg.
__global__ __launch_bounds__(256, 3) void k_attn(
    const u16* __restrict__ Q, const u16* __restrict__ K,
    const u16* __restrict__ Vt, u16* __restrict__ O) {
  __shared__ u16 lKV[2][8192];     // [buf][ K: 4096 u16 | V: 4096 u16 ]
  const int x = blockIdx.x;
  const int bh = ((x & 7) << 3) | ((x >> 3) & 7);
  const int qt = 15 - (x >> 6);
  const int tid = threadIdx.x, lane = tid & 63, w = tid >> 6;
  const int l31 = lane & 31, h = lane >> 5;
  const int qbase = qt * 128 + w * 32;
  const u16* Kb = K + (size_t)bh * 2048 * 64;
  const u16* Vb = Vt + (size_t)bh * 64 * 2048;

  auto stage_dma = [&](int kv0, int buf) {
    char* base = (char*)&lKV[buf][0];
#pragma unroll
    for (int i = 0; i < 2; i++) {
      const int sg = 2 * w + i;            // sweeps 0..7 across 4 waves, x2 (K,V)
      const int r = lane ^ sg;
      gll16(Kb + (size_t)(kv0 + r) * 64 + sg * 8, base + sg * 1024);
      gll16(Vb + (size_t)r * 2048 + kv0 + sg * 8, base + 8192 + sg * 1024);
    }
  };

  // Q B-frags: lane l -> q col = l31, k(dh) = ks*16 + 8h + e
  s8v qf[4];
#pragma unroll
  for (int ks = 0; ks < 4; ks++)
    qf[ks] = *(const s8v*)(Q + (size_t)(bh * 2048 + qbase + l31) * 64 + ks * 16 + 8 * h);

  f32x16 accO0, accO1;
#pragma unroll
  for (int i = 0; i < 16; i++) { accO0[i] = 0.f; accO1[i] = 0.f; }
  float mrun = -1e30f, lrun = 0.f;

  const int ntile = 2 * qt + 2;
  stage_dma(0, 0);

  for (int t = 0; t < ntile; ++t) {
    const int kv0 = t * 64;
    asm volatile("s_waitcnt vmcnt(0)" ::: "memory");   // buf[t&1] DMA complete
    __builtin_amdgcn_s_barrier();
    __builtin_amdgcn_sched_barrier(0);
    if (t + 1 < ntile) stage_dma((t + 1) * 64, (t + 1) & 1);
    const u16* base = &lKV[t & 1][0];

    if (kv0 <= qbase + 31) {               // wave-uniform causal skip
      // ---- swapped QK^T: S^T[kv][q], one q column per lane ----
      f32x16 st0, st1;
#pragma unroll
      for (int i = 0; i < 16; i++) { st0[i] = 0.f; st1[i] = 0.f; }
      __builtin_amdgcn_s_setprio(1);
#pragma unroll
      for (int ks = 0; ks < 4; ks++) {
        const int sl = 2 * ks + h;
        s8v a0 = *(const s8v*)&base[(sl * 64 + (l31 ^ sl)) * 8];
        s8v a1 = *(const s8v*)&base[(sl * 64 + ((32 + l31) ^ sl)) * 8];
        st0 = __builtin_amdgcn_mfma_f32_32x32x16_bf16(a0, qf[ks], st0, 0, 0, 0);
        st1 = __builtin_amdgcn_mfma_f32_32x32x16_bf16(a1, qf[ks], st1, 0, 0, 0);
      }
      __builtin_amdgcn_s_setprio(0);
      // ---- causal mask (diagonal tiles only) ----
      if (kv0 + 63 > qbase) {
        const int dq = qbase + l31 - kv0;  // kv_local <= dq allowed
#pragma unroll
        for (int r = 0; r < 16; r++) {
          const int kl = (r & 3) + 8 * (r >> 2) + 4 * h;
          if (kl > dq) st0[r] = -1e30f;
          if (kl + 32 > dq) st1[r] = -1e30f;
        }
      }
      // ---- online softmax, defer-max (T13) ----
      float mx = st0[0];
#pragma unroll
      for (int r = 1; r < 16; r++) mx = fmaxf(mx, st0[r]);
#pragma unroll
      for (int r = 0; r < 16; r++) mx = fmaxf(mx, st1[r]);
      mx = fmaxf(mx, __shfl_xor(mx, 32));
      if (!__all(mx <= mrun + 11.0f)) {
        const float mnew = fmaxf(mrun, mx);
        const float f = exp2f(mrun - mnew);
        lrun *= f;
#pragma unroll
        for (int r = 0; r < 16; r++) { accO0[r] *= f; accO1[r] *= f; }
        mrun = mnew;
      }
      float s = 0.f;
#pragma unroll
      for (int r = 0; r < 16; r++) { st0[r] = exp2f(st0[r] - mrun); s += st0[r]; }
#pragma unroll
      for (int r = 0; r < 16; r++) { st1[r] = exp2f(st1[r] - mrun); s += st1[r]; }
      s += __shfl_xor(s, 32);
      lrun += s;
      // ---- P -> bf16 in-register ----
      u32 W0[8], W1[8];
#pragma unroll
      for (int a = 0; a < 4; a++) {
        W0[2 * a]     = cvtpk(st0[4 * a], st0[4 * a + 1]);
        W0[2 * a + 1] = cvtpk(st0[4 * a + 2], st0[4 * a + 3]);
        W1[2 * a]     = cvtpk(st1[4 * a], st1[4 * a + 1]);
        W1[2 * a + 1] = cvtpk(st1[4 * a + 2], st1[4 * a + 3]);
      }
      // ---- PV: O^T[dh][q] += Vt @ P, B-frag via permlane32_swap ----
      __builtin_amdgcn_s_setprio(1);
#pragma unroll
      for (int ks = 0; ks < 4; ks++) {
        const int kp = ks & 1;
        u32 x0 = (ks < 2) ? W0[4 * kp]     : W1[4 * kp];
        u32 y0 = (ks < 2) ? W0[4 * kp + 2] : W1[4 * kp + 2];
        u32 x1 = (ks < 2) ? W0[4 * kp + 1] : W1[4 * kp + 1];
        u32 y1 = (ks < 2) ? W0[4 * kp + 3] : W1[4 * kp + 3];
        plswap(x0, y0);
        plswap(x1, y1);
        union { u32 u[4]; s8v v; } fb;
        fb.u[0] = x0; fb.u[1] = x1; fb.u[2] = y0; fb.u[3] = y1;
        const int sl = 2 * ks + h;
        s8v va0 = *(const s8v*)&base[4096 + (sl * 64 + (l31 ^ sl)) * 8];
        s8v va1 = *(const s8v*)&base[4096 + (sl * 64 + ((32 + l31) ^ sl)) * 8];
        accO0 = __builtin_amdgcn_mfma_f32_32x32x16_bf16(va0, fb.v, accO0, 0, 0, 0);
        accO1 = __builtin_amdgcn_mfma_f32_32x32x16_bf16(va1, fb.v, accO1, 0, 0, 0);
      }
      __builtin_amdgcn_s_setprio(0);
    }
  }

  // ---- epilogue: O = O^T / l, merge heads, 8B stores ----
  const int b_ = bh >> 4, h_ = bh & 15;
  const float rinv = 1.0f / lrun;
  u16* Ob = O + (size_t)(b_ * 2048 + qbase + l31) * 1024 + h_ * 64;
#pragma unroll
  for (int a = 0; a < 4; a++) {
    u32x2 o0, o1;
    o0[0] = cvtpk(accO0[4 * a] * rinv, accO0[4 * a + 1] * rinv);
    o0[1] = cvtpk(accO0[4 * a + 2] * rinv, accO0[4 * a + 3] * rinv);
    o1[0] = cvtpk(accO1[4 * a] * rinv, accO1[4 * a + 1] * rinv);
    o1[1] = cvtpk(accO1[4 * a + 2] * rinv, accO1[4 * a + 3] * rinv);
    *(u32x2*)(Ob + 8 * a + 4 * h) = o0;
    *(u32x2*)(Ob + 32 + 8 * a + 4 * h) = o1;
  }
}

extern "C" void kernel_launch(void* const* d_in, const int* in_sizes, int n_in,
                              void* d_out, int out_size, void* d_ws, size_t ws_size,
                              hipStream_t stream) {
  const float* x      = (const float*)d_in[0];
  const float* w_attn = (const float*)d_in[1];
  const float* b_attn = (const float*)d_in[2];
  const float* w_proj = (const float*)d_in[3];
  const float* b_proj = (const float*)d_in[4];
  float* out = (float*)d_out;

  u16* ws  = (u16*)d_ws;
  u16* xb  = ws;                   // x bf16 [8192][1024]; reused as attn-out
  u16* wTa = xb + 8388608;         // w_attn^T bf16 [3072][1024]
  u16* wTp = wTa + 3145728;        // w_proj^T bf16 [1024][1024]
  u16* qb  = wTp + 1048576;        // [64 bh][2048][64], pre-scaled 0.125*log2e
  u16* kb  = qb + 8388608;         // [64 bh][2048][64]
  u16* vb  = kb + 8388608;         // [64 bh][64][2048]  (transposed)

  k_cvt<<<8192, 256, 0, stream>>>(x, xb, 2097152);
  k_tr<<<dim3(96, 32), dim3(32, 8), 0, stream>>>(w_attn, wTa, 1024, 3072);
  k_tr<<<dim3(32, 32), dim3(32, 8), 0, stream>>>(w_proj, wTp, 1024, 1024);
  // QKV: 256x128 tile, grid 24x32 = 768 blocks = exactly 3 rounds at 1/CU
  k_gemm<0, 1024><<<dim3(24, 32), 512, 0, stream>>>(
      xb, wTa, b_attn, qb, kb, vb, nullptr, 8192, 3072);
  k_attn<<<1024, 256, 0, stream>>>(qb, kb, vb, xb);
  // proj: 256x128 tile, grid 8x32 = 256 blocks = exactly 1 round
  k_gemm<1, 1024><<<dim3(8, 32), 512, 0, stream>>>(
      xb, wTp, b_proj, nullptr, nullptr, nullptr, out, 8192, 1024);
}

// Round 8
// 184.068 us; speedup vs baseline: 1.1124x; 1.0284x over previous
//
#include <hip/hip_runtime.h>

// GPT-2 attention block, B=4 S=2048 D=1024 H=16 DH=64, f32 in/out.
// QKV GEMM: m201-style 8-phase 256x256 template (BK=64, 8 waves 2Mx4N,
//           128KB LDS 2dbuf x 4 slots, counted vmcnt, setprio'd MFMA).
// proj GEMM: R4-proven 128x128, 3-buffer counted-vmcnt pipeline.
// Attention: 32x32x16 bf16 MFMA, swapped operands, in-register softmax.
// Layouts (gfx950):
//   16x16x32: A[l&15][8*(l>>4)+e], B[l&15][8*(l>>4)+e], D[4*(l>>4)+r][l&15]
//   32x32x16: A[l&31][8*(l>>5)+e], B[l&31][8*(l>>5)+e],
//             D[(r&3)+8*(r>>2)+4*(l>>5)][l&31]

typedef short  s8v   __attribute__((ext_vector_type(8)));  // 8 bf16 (16B)
typedef float  f32x4 __attribute__((ext_vector_type(4)));
typedef float  f32x16 __attribute__((ext_vector_type(16)));
typedef unsigned short u16;
typedef u16    u16x4 __attribute__((ext_vector_type(4)));
typedef unsigned int u32;
typedef u32    u32x2 __attribute__((ext_vector_type(2)));

__device__ __forceinline__ u16 f2b(float f) {
  union { float f; unsigned u; } v; v.f = f;
  unsigned r = v.u + 0x7FFFu + ((v.u >> 16) & 1u);   // RNE
  return (u16)(r >> 16);
}
__device__ __forceinline__ u32 cvtpk(float lo, float hi) {   // bf16(lo)|bf16(hi)<<16
  u32 r; asm("v_cvt_pk_bf16_f32 %0, %1, %2" : "=v"(r) : "v"(lo), "v"(hi)); return r;
}
__device__ __forceinline__ void plswap(u32 &d, u32 &s) {
  asm volatile("v_permlane32_swap_b32 %0, %1" : "+v"(d), "+v"(s));
}
__device__ __forceinline__ void gll16(const void* g, void* l) {
  __builtin_amdgcn_global_load_lds((const __attribute__((address_space(1))) void*)g,
                                   (__attribute__((address_space(3))) void*)l, 16, 0, 0);
}

#define QSCALE 0.18033688011112042f   // 0.125 * log2(e): softmax in exp2 domain

// ---------------- f32 -> bf16 elementwise ----------------
__global__ __launch_bounds__(256) void k_cvt(const float* __restrict__ in,
                                             u16* __restrict__ out, int n4) {
  int t = blockIdx.x * 256 + threadIdx.x;
  if (t < n4) {
    f32x4 f = ((const f32x4*)in)[t];
    u16x4 o;
    o[0] = f2b(f[0]); o[1] = f2b(f[1]); o[2] = f2b(f[2]); o[3] = f2b(f[3]);
    ((u16x4*)out)[t] = o;
  }
}

// ---------------- f32 [R][C] -> bf16 [C][R] transpose ----------------
__global__ __launch_bounds__(256) void k_tr(const float* __restrict__ in,
                                            u16* __restrict__ out, int R, int C) {
  __shared__ float tile[32][33];
  int c0 = blockIdx.x * 32, r0 = blockIdx.y * 32;
  int tx = threadIdx.x, ty = threadIdx.y;
#pragma unroll
  for (int j = 0; j < 4; j++)
    tile[ty + j * 8][tx] = in[(size_t)(r0 + ty + j * 8) * C + c0 + tx];
  __syncthreads();
#pragma unroll
  for (int j = 0; j < 4; j++)
    out[(size_t)(c0 + ty + j * 8) * R + r0 + tx] = f2b(tile[tx][ty + j * 8]);
}

// ================= QKV GEMM: 8-phase 256x256 template =================
// C[M,N] = A[M,K] @ Bt[N,K]^T (+bias), scatter epilogue to q/k/v.
// 8 waves (wm=w>>2, wn=w&3), wave tile 128x64, acc[8][4].
// LDS: L[buf][slot A0,A1,B0,B1][128 rows x 64 u16], slot16 ^= row&7 swizzle.
// Schedule per iter j (tiles 2j from buf0, 2j+1 from buf1):
//   P1-P4 stage tile 2j+1 -> buf1 slots 0..3 (read P5-P8 this iter)
//   P5-P8 stage tile 2j+2 -> buf0 slots 0..3 (read next iter, guard j<7)
//   vmcnt(2) at P1/P5 (drain all but own phase's 2 loads); odd phases read
//   12 x ds_read_b128; every phase: barrier, lgkm0, 16 MFMA, barrier.
template <int KDIM>
__global__ __launch_bounds__(512, 1) void k_gemm8(
    const u16* __restrict__ A, const u16* __restrict__ Bt,
    const float* __restrict__ bias,
    u16* __restrict__ qb, u16* __restrict__ kb, u16* __restrict__ vb) {
  __shared__ u16 L[2][4][8192];    // 128 KB
  const int tid = threadIdx.x;
  const int lane = tid & 63, w = tid >> 6;
  const int wm = w >> 2, wn = w & 3;
  const int lr = lane & 15, lg = lane >> 4;
  const int rIn = lane >> 3;                        // row within 8-row sweep
  const int cSwz = ((lane & 7) ^ (lane >> 3)) * 16; // pre-swizzled src col (B)

  const int nwg = gridDim.x * gridDim.y;
  const int bid = blockIdx.y * gridDim.x + blockIdx.x;
  const int swz = (bid & 7) * (nwg >> 3) + (bid >> 3);
  const int m0 = (swz / gridDim.x) * 256, n0 = (swz % gridDim.x) * 256;

  const size_t K2 = (size_t)KDIM * 2;
  const char* gAc = (const char*)A + (size_t)m0 * K2;
  const char* gBc = (const char*)Bt + (size_t)n0 * K2;

#define STAGE2(KT, BUF, SLOT) do {                                             \
    const char* g_ = ((SLOT) < 2 ? gAc : gBc);                                 \
    const int h_ = (SLOT) & 1;                                                 \
    _Pragma("unroll") for (int i_ = 0; i_ < 2; i_++) {                         \
      const int sg_ = 8 * i_ + w;                                              \
      gll16(g_ + (size_t)(h_ * 128 + 8 * sg_ + rIn) * K2 +                     \
                (size_t)(KT) * 128 + cSwz,                                     \
            (char*)&L[BUF][SLOT][0] + sg_ * 1024);                             \
    }                                                                          \
  } while (0)

  s8v af[8], bf[4];
#define READS(BUF, KS) do {                                                    \
    const u16* As_ = &L[BUF][wm][0];                                           \
    const u16* Bs_ = &L[BUF][2 + (wn >> 1)][0];                                \
    _Pragma("unroll") for (int m_ = 0; m_ < 8; m_++) {                         \
      const int r_ = m_ * 16 + lr;                                             \
      af[m_] = *(const s8v*)&As_[r_ * 64 + ((((KS) << 2) | lg) ^ (r_ & 7)) * 8]; } \
    _Pragma("unroll") for (int n_ = 0; n_ < 4; n_++) {                         \
      const int r_ = (wn & 1) * 64 + n_ * 16 + lr;                             \
      bf[n_] = *(const s8v*)&Bs_[r_ * 64 + ((((KS) << 2) | lg) ^ (r_ & 7)) * 8]; } \
  } while (0)

  f32x4 acc[8][4];
#pragma unroll
  for (int m = 0; m < 8; m++)
#pragma unroll
    for (int n = 0; n < 4; n++) acc[m][n] = (f32x4){0.f, 0.f, 0.f, 0.f};

#define MFMAH(MH)                                                              \
  __builtin_amdgcn_s_setprio(1);                                               \
  _Pragma("unroll") for (int mm_ = 0; mm_ < 4; mm_++)                          \
  _Pragma("unroll") for (int nn_ = 0; nn_ < 4; nn_++)                          \
    acc[(MH) * 4 + mm_][nn_] = __builtin_amdgcn_mfma_f32_16x16x32_bf16(        \
        af[(MH) * 4 + mm_], bf[nn_], acc[(MH) * 4 + mm_][nn_], 0, 0, 0);       \
  __builtin_amdgcn_s_setprio(0);

  // prologue: tile 0 -> buf0 (4 slots, 8 stmts), full drain
  STAGE2(0, 0, 0); STAGE2(0, 0, 1); STAGE2(0, 0, 2); STAGE2(0, 0, 3);
  asm volatile("s_waitcnt vmcnt(0)" ::: "memory");
  __builtin_amdgcn_s_barrier();

  for (int j = 0; j < 8; ++j) {
    const int tO = 2 * j + 1, tE = 2 * j + 2;
    // ---- P1: stage buf1.A0, cold-read buf0 k0, MFMA m0-3 ----
    STAGE2(tO, 1, 0);
    asm volatile("s_waitcnt vmcnt(2)" ::: "memory");
    __builtin_amdgcn_s_barrier();
    __builtin_amdgcn_sched_barrier(0);
    READS(0, 0);
    asm volatile("s_waitcnt lgkmcnt(0)" ::: "memory");
    __builtin_amdgcn_sched_barrier(0);
    MFMAH(0)
    __builtin_amdgcn_s_barrier();
    // ---- P2 ----
    STAGE2(tO, 1, 1);
    __builtin_amdgcn_s_barrier();
    MFMAH(1)
    __builtin_amdgcn_s_barrier();
    // ---- P3: warm-read buf0 k1 (issued early), MFMA m0-3 ----
    STAGE2(tO, 1, 2);
    READS(0, 1);
    asm volatile("s_waitcnt lgkmcnt(8)" ::: "memory");
    __builtin_amdgcn_s_barrier();
    asm volatile("s_waitcnt lgkmcnt(0)" ::: "memory");
    __builtin_amdgcn_sched_barrier(0);
    MFMAH(0)
    __builtin_amdgcn_s_barrier();
    // ---- P4 ----
    STAGE2(tO, 1, 3);
    __builtin_amdgcn_s_barrier();
    MFMAH(1)
    __builtin_amdgcn_s_barrier();
    // ---- P5: stage buf0.A0 (tile 2j+2), cold-read buf1 k0 ----
    if (j < 7) {
      STAGE2(tE, 0, 0);
      asm volatile("s_waitcnt vmcnt(2)" ::: "memory");
    } else {
      asm volatile("s_waitcnt vmcnt(0)" ::: "memory");
    }
    __builtin_amdgcn_s_barrier();
    __builtin_amdgcn_sched_barrier(0);
    READS(1, 0);
    asm volatile("s_waitcnt lgkmcnt(0)" ::: "memory");
    __builtin_amdgcn_sched_barrier(0);
    MFMAH(0)
    __builtin_amdgcn_s_barrier();
    // ---- P6 ----
    if (j < 7) STAGE2(tE, 0, 1);
    __builtin_amdgcn_s_barrier();
    MFMAH(1)
    __builtin_amdgcn_s_barrier();
    // ---- P7 ----
    if (j < 7) STAGE2(tE, 0, 2);
    READS(1, 1);
    asm volatile("s_waitcnt lgkmcnt(8)" ::: "memory");
    __builtin_amdgcn_s_barrier();
    asm volatile("s_waitcnt lgkmcnt(0)" ::: "memory");
    __builtin_amdgcn_sched_barrier(0);
    MFMAH(0)
    __builtin_amdgcn_s_barrier();
    // ---- P8 ----
    if (j < 7) STAGE2(tE, 0, 3);
    __builtin_amdgcn_s_barrier();
    MFMAH(1)
    __builtin_amdgcn_s_barrier();
  }
#undef STAGE2
#undef READS
#undef MFMAH

  // ---- epilogue: scatter q/k [bh][S][64] (q pre-scaled), v^T [bh][64][S] ----
#pragma unroll
  for (int m = 0; m < 8; m++) {
#pragma unroll
    for (int n = 0; n < 4; n++) {
      const int col = n0 + wn * 64 + n * 16 + lr;
      const float bb = bias[col];
      const int row0 = m0 + wm * 128 + m * 16 + 4 * lg;
      const int which = col >> 10, d = col & 1023, hh = d >> 6, dh = d & 63;
      const int b = row0 >> 11, s = row0 & 2047;
      if (which == 2) {
        u16x4 ov;
#pragma unroll
        for (int r = 0; r < 4; r++) ov[r] = f2b(acc[m][n][r] + bb);
        *(u16x4*)(vb + ((size_t)((b * 16 + hh) * 64 + dh)) * 2048 + s) = ov;
      } else {
        u16* dst = which == 0 ? qb : kb;
        const float sc = which == 0 ? QSCALE : 1.0f;
#pragma unroll
        for (int r = 0; r < 4; r++)
          dst[(size_t)((b * 16 + hh) * 2048 + s + r) * 64 + dh] = f2b((acc[m][n][r] + bb) * sc);
      }
    }
  }
}

// ================= proj GEMM: R4-proven 128x128 pipeline =================
__device__ __forceinline__ void gemm_tile(const u16* bA, const u16* bB,
                                          f32x4 (&acc)[4][4],
                                          int wr, int wc, int lr, int lg) {
  s8v af[4], bfr[4];
#pragma unroll
  for (int m = 0; m < 4; m++) {
    const int row = wr + m * 16 + lr;
    af[m] = *(const s8v*)&bA[row * 32 + (lg ^ ((row >> 1) & 3)) * 8];
  }
#pragma unroll
  for (int n = 0; n < 4; n++) {
    const int row = wc + n * 16 + lr;
    bfr[n] = *(const s8v*)&bB[row * 32 + (lg ^ ((row >> 1) & 3)) * 8];
  }
  __builtin_amdgcn_s_setprio(1);
#pragma unroll
  for (int m = 0; m < 4; m++)
#pragma unroll
    for (int n = 0; n < 4; n++)
      acc[m][n] = __builtin_amdgcn_mfma_f32_16x16x32_bf16(af[m], bfr[n], acc[m][n], 0, 0, 0);
  __builtin_amdgcn_s_setprio(0);
}

__global__ __launch_bounds__(256, 3) void k_gemmP(
    const u16* __restrict__ A, const u16* __restrict__ Bt,
    const float* __restrict__ bias, float* __restrict__ outf, int M, int N, int K) {
  __shared__ u16 lA[3][4096];     // [buf][128 rows][32 cols], 16B-cell swizzled
  __shared__ u16 lB[3][4096];
  const int tid = threadIdx.x;
  const int lane = tid & 63, w = tid >> 6;
  const int wr = (w >> 1) * 64, wc = (w & 1) * 64;
  const int lr = lane & 15, lg = lane >> 4;

  const int nwg = gridDim.x * gridDim.y;
  const int bid = blockIdx.y * gridDim.x + blockIdx.x;
  const int swz = (bid & 7) * (nwg >> 3) + (bid >> 3);
  const int m0 = (swz / gridDim.x) * 128, n0 = (swz % gridDim.x) * 128;

  const int rr = lane >> 2;
  const int cb = ((lane & 3) ^ ((lane >> 3) & 3)) * 16;
  const size_t K2 = (size_t)K * 2;
  const char* gAc = (const char*)A + (size_t)m0 * K2;
  const char* gBc = (const char*)Bt + (size_t)n0 * K2;

  auto stage = [&](int kt, int buf) {
    const size_t ko = (size_t)kt * 64 + cb;
    char* dA = (char*)&lA[buf][0];
    char* dB = (char*)&lB[buf][0];
    gll16(gAc + (size_t)(32 * w + rr) * K2 + ko,      dA + (2 * w) * 1024);
    gll16(gAc + (size_t)(32 * w + 16 + rr) * K2 + ko, dA + (2 * w + 1) * 1024);
    gll16(gBc + (size_t)(32 * w + rr) * K2 + ko,      dB + (2 * w) * 1024);
    gll16(gBc + (size_t)(32 * w + 16 + rr) * K2 + ko, dB + (2 * w + 1) * 1024);
  };

  f32x4 acc[4][4];
#pragma unroll
  for (int m = 0; m < 4; m++)
#pragma unroll
    for (int n = 0; n < 4; n++) acc[m][n] = (f32x4){0.f, 0.f, 0.f, 0.f};

  const int nk = K / 32;
  stage(0, 0);
  if (nk > 1) stage(1, 1);

#define STEP(T, CB, SB)                                                     \
  if ((T) < nk) {                                                           \
    if ((T) + 1 < nk) { asm volatile("s_waitcnt vmcnt(4)" ::: "memory"); }  \
    else              { asm volatile("s_waitcnt vmcnt(0)" ::: "memory"); }  \
    __builtin_amdgcn_s_barrier();                                           \
    __builtin_amdgcn_sched_barrier(0);                                      \
    if ((T) + 2 < nk) stage((T) + 2, (SB));                                 \
    gemm_tile(&lA[(CB)][0], &lB[(CB)][0], acc, wr, wc, lr, lg);             \
  }

  for (int t0 = 0; t0 < nk; t0 += 3) {
    STEP(t0,     0, 2)
    STEP(t0 + 1, 1, 0)
    STEP(t0 + 2, 2, 1)
  }
#undef STEP

#pragma unroll
  for (int m = 0; m < 4; m++) {
#pragma unroll
    for (int n = 0; n < 4; n++) {
      const int col = n0 + wc + n * 16 + lr;
      const float bb = bias[col];
      const int row0 = m0 + wr + m * 16 + 4 * lg;
#pragma unroll
      for (int r = 0; r < 4; r++)
        outf[(size_t)(row0 + r) * N + col] = acc[m][n][r] + bb;
    }
  }
}

// ---------------- flash attention, causal, swapped 32x32 MFMA, in-reg softmax ----
__global__ __launch_bounds__(256, 3) void k_attn(
    const u16* __restrict__ Q, const u16* __restrict__ K,
    const u16* __restrict__ Vt, u16* __restrict__ O) {
  __shared__ u16 lKV[2][8192];     // [buf][ K: 4096 u16 | V: 4096 u16 ]
  const int x = blockIdx.x;
  const int bh = ((x & 7) << 3) | ((x >> 3) & 7);
  const int qt = 15 - (x >> 6);
  const int tid = threadIdx.x, lane = tid & 63, w = tid >> 6;
  const int l31 = lane & 31, h = lane >> 5;
  const int qbase = qt * 128 + w * 32;
  const u16* Kb = K + (size_t)bh * 2048 * 64;
  const u16* Vb = Vt + (size_t)bh * 64 * 2048;

  auto stage_dma = [&](int kv0, int buf) {
    char* base = (char*)&lKV[buf][0];
#pragma unroll
    for (int i = 0; i < 2; i++) {
      const int sg = 2 * w + i;
      const int r = lane ^ sg;
      gll16(Kb + (size_t)(kv0 + r) * 64 + sg * 8, base + sg * 1024);
      gll16(Vb + (size_t)r * 2048 + kv0 + sg * 8, base + 8192 + sg * 1024);
    }
  };

  s8v qf[4];
#pragma unroll
  for (int ks = 0; ks < 4; ks++)
    qf[ks] = *(const s8v*)(Q + (size_t)(bh * 2048 + qbase + l31) * 64 + ks * 16 + 8 * h);

  f32x16 accO0, accO1;
#pragma unroll
  for (int i = 0; i < 16; i++) { accO0[i] = 0.f; accO1[i] = 0.f; }
  float mrun = -1e30f, lrun = 0.f;

  const int ntile = 2 * qt + 2;
  stage_dma(0, 0);

  for (int t = 0; t < ntile; ++t) {
    const int kv0 = t * 64;
    asm volatile("s_waitcnt vmcnt(0)" ::: "memory");
    __builtin_amdgcn_s_barrier();
    __builtin_amdgcn_sched_barrier(0);
    if (t + 1 < ntile) stage_dma((t + 1) * 64, (t + 1) & 1);
    const u16* base = &lKV[t & 1][0];

    if (kv0 <= qbase + 31) {
      f32x16 st0, st1;
#pragma unroll
      for (int i = 0; i < 16; i++) { st0[i] = 0.f; st1[i] = 0.f; }
      __builtin_amdgcn_s_setprio(1);
#pragma unroll
      for (int ks = 0; ks < 4; ks++) {
        const int sl = 2 * ks + h;
        s8v a0 = *(const s8v*)&base[(sl * 64 + (l31 ^ sl)) * 8];
        s8v a1 = *(const s8v*)&base[(sl * 64 + ((32 + l31) ^ sl)) * 8];
        st0 = __builtin_amdgcn_mfma_f32_32x32x16_bf16(a0, qf[ks], st0, 0, 0, 0);
        st1 = __builtin_amdgcn_mfma_f32_32x32x16_bf16(a1, qf[ks], st1, 0, 0, 0);
      }
      __builtin_amdgcn_s_setprio(0);
      if (kv0 + 63 > qbase) {
        const int dq = qbase + l31 - kv0;
#pragma unroll
        for (int r = 0; r < 16; r++) {
          const int kl = (r & 3) + 8 * (r >> 2) + 4 * h;
          if (kl > dq) st0[r] = -1e30f;
          if (kl + 32 > dq) st1[r] = -1e30f;
        }
      }
      float mx = st0[0];
#pragma unroll
      for (int r = 1; r < 16; r++) mx = fmaxf(mx, st0[r]);
#pragma unroll
      for (int r = 0; r < 16; r++) mx = fmaxf(mx, st1[r]);
      mx = fmaxf(mx, __shfl_xor(mx, 32));
      if (!__all(mx <= mrun + 11.0f)) {
        const float mnew = fmaxf(mrun, mx);
        const float f = exp2f(mrun - mnew);
        lrun *= f;
#pragma unroll
        for (int r = 0; r < 16; r++) { accO0[r] *= f; accO1[r] *= f; }
        mrun = mnew;
      }
      float s = 0.f;
#pragma unroll
      for (int r = 0; r < 16; r++) { st0[r] = exp2f(st0[r] - mrun); s += st0[r]; }
#pragma unroll
      for (int r = 0; r < 16; r++) { st1[r] = exp2f(st1[r] - mrun); s += st1[r]; }
      s += __shfl_xor(s, 32);
      lrun += s;
      u32 W0[8], W1[8];
#pragma unroll
      for (int a = 0; a < 4; a++) {
        W0[2 * a]     = cvtpk(st0[4 * a], st0[4 * a + 1]);
        W0[2 * a + 1] = cvtpk(st0[4 * a + 2], st0[4 * a + 3]);
        W1[2 * a]     = cvtpk(st1[4 * a], st1[4 * a + 1]);
        W1[2 * a + 1] = cvtpk(st1[4 * a + 2], st1[4 * a + 3]);
      }
      __builtin_amdgcn_s_setprio(1);
#pragma unroll
      for (int ks = 0; ks < 4; ks++) {
        const int kp = ks & 1;
        u32 x0 = (ks < 2) ? W0[4 * kp]     : W1[4 * kp];
        u32 y0 = (ks < 2) ? W0[4 * kp + 2] : W1[4 * kp + 2];
        u32 x1 = (ks < 2) ? W0[4 * kp + 1] : W1[4 * kp + 1];
        u32 y1 = (ks < 2) ? W0[4 * kp + 3] : W1[4 * kp + 3];
        plswap(x0, y0);
        plswap(x1, y1);
        union { u32 u[4]; s8v v; } fb;
        fb.u[0] = x0; fb.u[1] = x1; fb.u[2] = y0; fb.u[3] = y1;
        const int sl = 2 * ks + h;
        s8v va0 = *(const s8v*)&base[4096 + (sl * 64 + (l31 ^ sl)) * 8];
        s8v va1 = *(const s8v*)&base[4096 + (sl * 64 + ((32 + l31) ^ sl)) * 8];
        accO0 = __builtin_amdgcn_mfma_f32_32x32x16_bf16(va0, fb.v, accO0, 0, 0, 0);
        accO1 = __builtin_amdgcn_mfma_f32_32x32x16_bf16(va1, fb.v, accO1, 0, 0, 0);
      }
      __builtin_amdgcn_s_setprio(0);
    }
  }

  const int b_ = bh >> 4, h_ = bh & 15;
  const float rinv = 1.0f / lrun;
  u16* Ob = O + (size_t)(b_ * 2048 + qbase + l31) * 1024 + h_ * 64;
#pragma unroll
  for (int a = 0; a < 4; a++) {
    u32x2 o0, o1;
    o0[0] = cvtpk(accO0[4 * a] * rinv, accO0[4 * a + 1] * rinv);
    o0[1] = cvtpk(accO0[4 * a + 2] * rinv, accO0[4 * a + 3] * rinv);
    o1[0] = cvtpk(accO1[4 * a] * rinv, accO1[4 * a + 1] * rinv);
    o1[1] = cvtpk(accO1[4 * a + 2] * rinv, accO1[4 * a + 3] * rinv);
    *(u32x2*)(Ob + 8 * a + 4 * h) = o0;
    *(u32x2*)(Ob + 32 + 8 * a + 4 * h) = o1;
  }
}

extern "C" void kernel_launch(void* const* d_in, const int* in_sizes, int n_in,
                              void* d_out, int out_size, void* d_ws, size_t ws_size,
                              hipStream_t stream) {
  const float* x      = (const float*)d_in[0];
  const float* w_attn = (const float*)d_in[1];
  const float* b_attn = (const float*)d_in[2];
  const float* w_proj = (const float*)d_in[3];
  const float* b_proj = (const float*)d_in[4];
  float* out = (float*)d_out;

  u16* ws  = (u16*)d_ws;
  u16* xb  = ws;                   // x bf16 [8192][1024]; reused as attn-out
  u16* wTa = xb + 8388608;         // w_attn^T bf16 [3072][1024]
  u16* wTp = wTa + 3145728;        // w_proj^T bf16 [1024][1024]
  u16* qb  = wTp + 1048576;        // [64 bh][2048][64], pre-scaled 0.125*log2e
  u16* kb  = qb + 8388608;         // [64 bh][2048][64]
  u16* vb  = kb + 8388608;         // [64 bh][64][2048]  (transposed)

  k_cvt<<<8192, 256, 0, stream>>>(x, xb, 2097152);
  k_tr<<<dim3(96, 32), dim3(32, 8), 0, stream>>>(w_attn, wTa, 1024, 3072);
  k_tr<<<dim3(32, 32), dim3(32, 8), 0, stream>>>(w_proj, wTp, 1024, 1024);
  // QKV: 256x256 8-phase template, grid 12x32 = 384 blocks
  k_gemm8<1024><<<dim3(12, 32), 512, 0, stream>>>(xb, wTa, b_attn, qb, kb, vb);
  k_attn<<<1024, 256, 0, stream>>>(qb, kb, vb, xb);
  // proj: R4-proven 128x128, grid 8x64 = 512 blocks (3/CU capacity)
  k_gemmP<<<dim3(8, 64), 256, 0, stream>>>(xb, wTp, b_proj, out, 8192, 1024, 1024);
}